// Round 4
// baseline (261.338 us; speedup 1.0000x reference)
//
#include <hip/hip_runtime.h>
#include <hip/hip_cooperative_groups.h>
#include <math.h>

#define NN 512
#define MM (NN * NN)          // 262144
#define HW (NN * NN)
#define CH 3

namespace cg = cooperative_groups;

__device__ __forceinline__ float dct_s(int k) {
    // s_0 = sqrt(1/512), s_k = sqrt(2/512)
    return (k == 0) ? 0.04419417382415922f : 0.0625f;
}

// ws layout (floats): Trp0, Trp1, Tcp0, Tcp1, Grp0, Grp1, Gcp0, Gcp1, partials
__global__ void __launch_bounds__(256) k_fused(
    const float* __restrict__ x, const float* __restrict__ att,
    const float* __restrict__ rw, const float* __restrict__ cw,
    float* __restrict__ out, float* __restrict__ ws)
{
    cg::grid_group grid = cg::this_grid();
    const int tid = threadIdx.x;
    const int bid = blockIdx.x;          // 0..511

    __shared__ float lds[2048];          // 8 KB, reused per phase
    __shared__ float sred[8];

    // ================= Phase 1: T partials (stage A) =================
    // T[h][wp] = sum_hp D[hp][h] * att[hp][wp] * rw[hp]   (row version)
    // Tc pre-scales by cw[wp].  K (hp) split in half across blocks.
    {
        const int kh  = bid & 1;          // hp half
        const int wph = (bid >> 1) & 1;   // wp half
        const int hg  = bid >> 2;         // 0..127
        const int h0  = hg * 4;
        const int wp  = wph * 256 + tid;
        const int hp0 = kh * 256;

        // stage D[hp0+t][h0+i] into lds[t*4+i] (computed, not loaded)
        {
            const int hp = hp0 + tid;
            const float s = dct_s(hp);
            #pragma unroll
            for (int i = 0; i < 4; ++i) {
                int m = ((2 * (h0 + i) + 1) * hp) & 2047;
                lds[tid * 4 + i] = s * cospif((float)m * (1.0f / 1024.0f));
            }
        }
        __syncthreads();

        float ar0 = 0.f, ar1 = 0.f, ar2 = 0.f, ar3 = 0.f;
        float as0 = 0.f, as1 = 0.f, as2 = 0.f, as3 = 0.f;
        const float* ap = att + hp0 * NN + wp;
        #pragma unroll 4
        for (int t = 0; t < 256; ++t) {
            float a = ap[t * NN];                 // coalesced
            float r = rw[hp0 + t];                // host data (scalar-safe)
            float4 d = *reinterpret_cast<const float4*>(&lds[t * 4]);
            float ra = r * a;
            ar0 += d.x * ra; as0 += d.x * a;
            ar1 += d.y * ra; as1 += d.y * a;
            ar2 += d.z * ra; as2 += d.z * a;
            ar3 += d.w * ra; as3 += d.w * a;
        }
        float c = cw[wp];
        float* Trp = ws + kh * MM;
        float* Tcp = ws + (2 + kh) * MM;
        Trp[(h0 + 0) * NN + wp] = ar0;  Tcp[(h0 + 0) * NN + wp] = as0 * c;
        Trp[(h0 + 1) * NN + wp] = ar1;  Tcp[(h0 + 1) * NN + wp] = as1 * c;
        Trp[(h0 + 2) * NN + wp] = ar2;  Tcp[(h0 + 2) * NN + wp] = as2 * c;
        Trp[(h0 + 3) * NN + wp] = ar3;  Tcp[(h0 + 3) * NN + wp] = as3 * c;
    }
    grid.sync();

    // ================= Phase 2: G partials (stage B) =================
    // G[h][w] = sum_wp T[h][wp] * D[wp][w].  K (wp) split in half.
    {
        const int kh = bid & 1;           // wp half
        const int wh = (bid >> 1) & 1;    // w half
        const int hg = bid >> 2;
        const int h0 = hg * 4;
        const int w  = wh * 256 + tid;
        const int wp0 = kh * 256;

        const float* Trp0 = ws;
        const float* Trp1 = ws + MM;
        const float* Tcp0 = ws + 2 * MM;
        const float* Tcp1 = ws + 3 * MM;

        // stage merged T tile: lds[t*8 + i] = Tr[h0+i][wp0+t], +4 for Tc
        #pragma unroll
        for (int i = 0; i < 4; ++i) {
            int idx = (h0 + i) * NN + wp0 + tid;   // coalesced vector loads
            lds[tid * 8 + i]     = Trp0[idx] + Trp1[idx];
            lds[tid * 8 + 4 + i] = Tcp0[idx] + Tcp1[idx];
        }
        __syncthreads();

        float gr0 = 0.f, gr1 = 0.f, gr2 = 0.f, gr3 = 0.f;
        float gc0 = 0.f, gc1 = 0.f, gc2 = 0.f, gc3 = 0.f;
        const int w2 = 2 * w + 1;
        #pragma unroll 4
        for (int t = 0; t < 256; ++t) {
            int wp = wp0 + t;
            int m = (w2 * wp) & 2047;
            float d = dct_s(wp) * cospif((float)m * (1.0f / 1024.0f));
            float4 a = *reinterpret_cast<const float4*>(&lds[t * 8]);
            float4 b = *reinterpret_cast<const float4*>(&lds[t * 8 + 4]);
            gr0 += a.x * d; gr1 += a.y * d; gr2 += a.z * d; gr3 += a.w * d;
            gc0 += b.x * d; gc1 += b.y * d; gc2 += b.z * d; gc3 += b.w * d;
        }
        float* Grp = ws + (4 + kh) * MM;
        float* Gcp = ws + (6 + kh) * MM;
        Grp[(h0 + 0) * NN + w] = gr0;  Gcp[(h0 + 0) * NN + w] = gc0;
        Grp[(h0 + 1) * NN + w] = gr1;  Gcp[(h0 + 1) * NN + w] = gc1;
        Grp[(h0 + 2) * NN + w] = gr2;  Gcp[(h0 + 2) * NN + w] = gc2;
        Grp[(h0 + 3) * NN + w] = gr3;  Gcp[(h0 + 3) * NN + w] = gc3;
    }
    grid.sync();

    // ================= Phase 3: batch reduction =================
    // out_partial[b] = sum_hw (sum_c x[b,c,hw]) * G[hw]
    {
        const int b  = bid >> 3;          // 0..63
        const int ck = bid & 7;           // 0..7
        const float* xb = x + (size_t)b * (CH * HW);
        const float* Grp0 = ws + 4 * MM;
        const float* Grp1 = ws + 5 * MM;
        const float* Gcp0 = ws + 6 * MM;
        const float* Gcp1 = ws + 7 * MM;
        const int hw0 = ck * (HW / 8);    // 32768-wide chunk

        float accr = 0.f, accc = 0.f;
        #pragma unroll 4
        for (int j = 0; j < 32; ++j) {
            int hw = hw0 + j * 1024 + tid * 4;
            float4 g0 = *(const float4*)(Grp0 + hw);
            float4 g1 = *(const float4*)(Grp1 + hw);
            float4 c0 = *(const float4*)(Gcp0 + hw);
            float4 c1 = *(const float4*)(Gcp1 + hw);
            float4 x0 = *(const float4*)(xb + hw);
            float4 x1 = *(const float4*)(xb + HW + hw);
            float4 x2 = *(const float4*)(xb + 2 * HW + hw);
            float sxx = x0.x + x1.x + x2.x;
            float sxy = x0.y + x1.y + x2.y;
            float sxz = x0.z + x1.z + x2.z;
            float sxw = x0.w + x1.w + x2.w;
            accr += (g0.x + g1.x) * sxx + (g0.y + g1.y) * sxy
                  + (g0.z + g1.z) * sxz + (g0.w + g1.w) * sxw;
            accc += (c0.x + c1.x) * sxx + (c0.y + c1.y) * sxy
                  + (c0.z + c1.z) * sxz + (c0.w + c1.w) * sxw;
        }
        for (int off = 32; off > 0; off >>= 1) {
            accr += __shfl_down(accr, off);
            accc += __shfl_down(accc, off);
        }
        int wid = tid >> 6;
        if ((tid & 63) == 0) { sred[wid] = accr; sred[4 + wid] = accc; }
        __syncthreads();
        if (tid == 0) {
            float r = sred[0] + sred[1] + sred[2] + sred[3];
            float c = sred[4] + sred[5] + sred[6] + sred[7];
            float* partials = ws + 8 * MM;
            partials[(b * 8 + ck) * 2 + 0] = r;
            partials[(b * 8 + ck) * 2 + 1] = c;
        }
    }
    grid.sync();

    // ================= Phase 4: finalize =================
    if (bid == 0 && tid < 64) {
        const float* partials = ws + 8 * MM;
        float r = 0.f, c = 0.f;
        #pragma unroll
        for (int i = 0; i < 8; ++i) {
            r += partials[(tid * 8 + i) * 2 + 0];
            c += partials[(tid * 8 + i) * 2 + 1];
        }
        const float inv = 1.0f / (float)(CH * HW);
        r *= inv; c *= inv;
        out[tid * 2 + 0] = 1.0f / (1.0f + expf(-c));   // col_out first
        out[tid * 2 + 1] = 1.0f / (1.0f + expf(-r));
    }
}

extern "C" void kernel_launch(void* const* d_in, const int* in_sizes, int n_in,
                              void* d_out, int out_size, void* d_ws, size_t ws_size,
                              hipStream_t stream) {
    const float* x   = (const float*)d_in[0];   // [64,3,512,512]
    const float* att = (const float*)d_in[1];   // [512,512]
    const float* rw  = (const float*)d_in[2];   // [512]
    const float* cw  = (const float*)d_in[3];   // [512]
    float* out = (float*)d_out;                 // [64,2]
    float* ws  = (float*)d_ws;                  // needs 8*MM + 1024 floats ≈ 8.4 MB

    void* args[] = { (void*)&x, (void*)&att, (void*)&rw, (void*)&cw,
                     (void*)&out, (void*)&ws };
    hipLaunchCooperativeKernel((const void*)k_fused, dim3(512), dim3(256),
                               args, 0, stream);
}

// Round 5
// 84.618 us; speedup vs baseline: 3.0884x; 3.0884x over previous
//
#include <hip/hip_runtime.h>
#include <math.h>

#define NN 512
#define MM (NN * NN)
#define HW (NN * NN)
#define CH 3

__device__ __forceinline__ float dct_s(int k) {
    // s_0 = sqrt(1/512), s_k = sqrt(2/512)
    return (k == 0) ? 0.04419417382415922f : 0.0625f;
}

// ---------------- Stage A: T[h][wp] ----------------
// Tr[h][wp] = sum_hp D[hp][h]*att[hp][wp]*rw[hp]
// Tc[h][wp] = cw[wp] * sum_hp D[hp][h]*att[hp][wp]
// 1024 blocks = 128 h-groups(4h) x 8 wp-eighths(64wp). 256 thr = 4 k-chunks x 64 lanes.
__global__ void __launch_bounds__(256) k_stageA(
    const float* __restrict__ att, const float* __restrict__ rw,
    const float* __restrict__ cw, float* __restrict__ Tr, float* __restrict__ Tc)
{
    __shared__ float sD[2048];        // [hp][i] = D[hp][h0+i], computed in-kernel
    __shared__ float sRw[512];
    __shared__ float sAcc[256 * 9];   // pad 9 -> conflict-free k-reduction
    const int tid = threadIdx.x;
    const int bx  = blockIdx.x;
    const int h0  = (bx >> 3) * 4;
    const int wp0 = (bx & 7) * 64;
    const int kc  = tid >> 6;
    const int wl  = tid & 63;
    const int wp  = wp0 + wl;
    const int hp0 = kc * 128;

    #pragma unroll
    for (int e = 0; e < 8; ++e) {                 // 2048 D entries, 8/thread
        int idx = tid * 8 + e;
        int hp = idx >> 2, i = idx & 3;
        int m = ((2 * (h0 + i) + 1) * hp) & 2047; // exact mod 4N
        sD[idx] = dct_s(hp) * cospif((float)m * (1.0f / 1024.0f));
    }
    sRw[tid] = rw[tid];
    sRw[256 + tid] = rw[256 + tid];
    __syncthreads();

    float ar0=0.f,ar1=0.f,ar2=0.f,ar3=0.f, as0=0.f,as1=0.f,as2=0.f,as3=0.f;
    #pragma unroll 4
    for (int t = 0; t < 128; ++t) {
        int hp = hp0 + t;
        float a = att[hp * NN + wp];              // coalesced 256B/wave
        float r = sRw[hp];                        // LDS broadcast
        float4 d = *reinterpret_cast<const float4*>(&sD[hp * 4]); // broadcast
        float ra = r * a;
        ar0 += d.x * ra; as0 += d.x * a;
        ar1 += d.y * ra; as1 += d.y * a;
        ar2 += d.z * ra; as2 += d.z * a;
        ar3 += d.w * ra; as3 += d.w * a;
    }
    float* sa = &sAcc[tid * 9];
    sa[0]=ar0; sa[1]=ar1; sa[2]=ar2; sa[3]=ar3;
    sa[4]=as0; sa[5]=as1; sa[6]=as2; sa[7]=as3;
    __syncthreads();
    if (tid < 64) {
        float v[8];
        #pragma unroll
        for (int j = 0; j < 8; ++j)
            v[j] = sAcc[(0*64 + tid)*9 + j] + sAcc[(1*64 + tid)*9 + j]
                 + sAcc[(2*64 + tid)*9 + j] + sAcc[(3*64 + tid)*9 + j];
        float c = cw[wp0 + tid];
        #pragma unroll
        for (int i = 0; i < 4; ++i) {
            Tr[(h0 + i) * NN + wp0 + tid] = v[i];
            Tc[(h0 + i) * NN + wp0 + tid] = v[4 + i] * c;
        }
    }
}

// ---------------- Stage B: G[h][w] = sum_wp T[h][wp] * D[wp][w] ----------------
// 1024 blocks = 128 h-groups(4h) x 8 w-eighths(64w). 256 thr = 4 k-chunks x 64 lanes.
// D[wp][w] computed on the fly (incremental phase); T staged in LDS.
__global__ void __launch_bounds__(256) k_stageB(
    const float* __restrict__ Tr, const float* __restrict__ Tc,
    float* __restrict__ Gr, float* __restrict__ Gc)
{
    __shared__ float sT[512 * 8];     // [wp][0..3]=Tr(h0..h0+3), [4..7]=Tc
    __shared__ float sAcc[256 * 9];
    const int tid = threadIdx.x;
    const int bx  = blockIdx.x;
    const int h0  = (bx >> 3) * 4;
    const int w0  = (bx & 7) * 64;
    const int kc  = tid >> 6;
    const int wl  = tid & 63;
    const int w   = w0 + wl;
    const int wp0 = kc * 128;

    #pragma unroll
    for (int i = 0; i < 4; ++i) {                 // coalesced global reads
        sT[tid * 8 + i]             = Tr[(h0 + i) * NN + tid];
        sT[tid * 8 + 4 + i]         = Tc[(h0 + i) * NN + tid];
        sT[(tid + 256) * 8 + i]     = Tr[(h0 + i) * NN + tid + 256];
        sT[(tid + 256) * 8 + 4 + i] = Tc[(h0 + i) * NN + tid + 256];
    }
    __syncthreads();

    float gr0=0.f,gr1=0.f,gr2=0.f,gr3=0.f, gc0=0.f,gc1=0.f,gc2=0.f,gc3=0.f;
    const int w2 = 2 * w + 1;
    int m = (w2 * wp0) & 2047;                    // incremental phase
    #pragma unroll 4
    for (int t = 0; t < 128; ++t) {
        int wp = wp0 + t;
        float s = (wp == 0) ? 0.04419417382415922f : 0.0625f;
        float d = s * cospif((float)m * (1.0f / 1024.0f));
        m = (m + w2) & 2047;
        float4 ta = *reinterpret_cast<const float4*>(&sT[wp * 8]);     // broadcast
        float4 tb = *reinterpret_cast<const float4*>(&sT[wp * 8 + 4]); // broadcast
        gr0 += ta.x * d; gr1 += ta.y * d; gr2 += ta.z * d; gr3 += ta.w * d;
        gc0 += tb.x * d; gc1 += tb.y * d; gc2 += tb.z * d; gc3 += tb.w * d;
    }
    float* sa = &sAcc[tid * 9];
    sa[0]=gr0; sa[1]=gr1; sa[2]=gr2; sa[3]=gr3;
    sa[4]=gc0; sa[5]=gc1; sa[6]=gc2; sa[7]=gc3;
    __syncthreads();
    if (tid < 64) {
        float v[8];
        #pragma unroll
        for (int j = 0; j < 8; ++j)
            v[j] = sAcc[(0*64 + tid)*9 + j] + sAcc[(1*64 + tid)*9 + j]
                 + sAcc[(2*64 + tid)*9 + j] + sAcc[(3*64 + tid)*9 + j];
        #pragma unroll
        for (int i = 0; i < 4; ++i) {
            Gr[(h0 + i) * NN + w0 + tid] = v[i];
            Gc[(h0 + i) * NN + w0 + tid] = v[4 + i];
        }
    }
}

// ---------------- Reduce: per-b dot with Gr/Gc ----------------
// grid (32, 64): 2048 blocks (8/CU). Same-ck blocks land on one XCD (L2 reuse of G).
__global__ void __launch_bounds__(256) k_reduce(
    const float* __restrict__ x, const float* __restrict__ Gr,
    const float* __restrict__ Gc, float* __restrict__ partials)
{
    const int b = blockIdx.y, ck = blockIdx.x, t = threadIdx.x;
    const float* xb = x + (size_t)b * (CH * HW);
    const int hw0 = ck * (HW / 32);               // 8192-wide chunk
    float accr = 0.f, accc = 0.f;
    #pragma unroll 4
    for (int j = 0; j < 8; ++j) {
        int hw = hw0 + j * 1024 + t * 4;
        float4 gr = *(const float4*)(Gr + hw);
        float4 gc = *(const float4*)(Gc + hw);
        float4 x0 = *(const float4*)(xb + hw);
        float4 x1 = *(const float4*)(xb + HW + hw);
        float4 x2 = *(const float4*)(xb + 2 * HW + hw);
        float sxx = x0.x + x1.x + x2.x;
        float sxy = x0.y + x1.y + x2.y;
        float sxz = x0.z + x1.z + x2.z;
        float sxw = x0.w + x1.w + x2.w;
        accr += gr.x * sxx + gr.y * sxy + gr.z * sxz + gr.w * sxw;
        accc += gc.x * sxx + gc.y * sxy + gc.z * sxz + gc.w * sxw;
    }
    for (int off = 32; off > 0; off >>= 1) {
        accr += __shfl_down(accr, off);
        accc += __shfl_down(accc, off);
    }
    __shared__ float sr[4], sc[4];
    int wid = t >> 6;
    if ((t & 63) == 0) { sr[wid] = accr; sc[wid] = accc; }
    __syncthreads();
    if (t == 0) {
        partials[(b * 32 + ck) * 2 + 0] = sr[0] + sr[1] + sr[2] + sr[3];
        partials[(b * 32 + ck) * 2 + 1] = sc[0] + sc[1] + sc[2] + sc[3];
    }
}

__global__ void k_final(const float* __restrict__ partials, float* __restrict__ out) {
    int b = threadIdx.x;   // 0..63
    float r = 0.f, c = 0.f;
    for (int i = 0; i < 32; ++i) {
        r += partials[(b * 32 + i) * 2 + 0];
        c += partials[(b * 32 + i) * 2 + 1];
    }
    const float inv = 1.0f / (float)(CH * HW);
    r *= inv; c *= inv;
    out[b * 2 + 0] = 1.0f / (1.0f + expf(-c));   // col_out first (stack order)
    out[b * 2 + 1] = 1.0f / (1.0f + expf(-r));
}

extern "C" void kernel_launch(void* const* d_in, const int* in_sizes, int n_in,
                              void* d_out, int out_size, void* d_ws, size_t ws_size,
                              hipStream_t stream) {
    const float* x   = (const float*)d_in[0];   // [64,3,512,512]
    const float* att = (const float*)d_in[1];   // [512,512]
    const float* rw  = (const float*)d_in[2];   // [512]
    const float* cw  = (const float*)d_in[3];   // [512]
    float* out = (float*)d_out;                 // [64,2]

    float* ws = (float*)d_ws;                   // 4*MM + 4096 floats ~ 4.2 MB
    float* Tr = ws;
    float* Tc = ws + 1 * MM;
    float* Gr = ws + 2 * MM;
    float* Gc = ws + 3 * MM;
    float* partials = ws + 4 * MM;              // 64*32*2 = 4096

    k_stageA<<<1024, 256, 0, stream>>>(att, rw, cw, Tr, Tc);
    k_stageB<<<1024, 256, 0, stream>>>(Tr, Tc, Gr, Gc);
    dim3 g(32, 64);
    k_reduce<<<g, 256, 0, stream>>>(x, Gr, Gc, partials);
    k_final<<<1, 64, 0, stream>>>(partials, out);
}